// Round 1
// baseline (5768.154 us; speedup 1.0000x reference)
//
#include <hip/hip_runtime.h>
#include <hip/hip_bf16.h>
#include <stdint.h>

// GCN encoder: h = relu(A(x@W1)+b1); hagg = A h; mu = hagg@Wmu+bmu; ls = hagg@Wls+bls
// A = symmetric-normalized adjacency with self-loops (dis[s]*dis[d] edge weights,
// dis[v]^2 self term).

static inline size_t align_up(size_t x, size_t a) { return (x + a - 1) / a * a; }

// ---------------- edge decode (int32 vs int64 robustness) ----------------

__global__ void detect_i64_kernel(const int* __restrict__ ei, int nwords_check, int* __restrict__ flag) {
    __shared__ int any_nz;
    if (threadIdx.x == 0) any_nz = 0;
    __syncthreads();
    int nz = 0;
    for (int i = threadIdx.x; i < nwords_check; i += blockDim.x) {
        if (ei[2 * i + 1] != 0) nz = 1;
    }
    if (nz) atomicOr(&any_nz, 1);
    __syncthreads();
    if (threadIdx.x == 0) flag[0] = any_nz ? 0 : 1;  // all-zero high words => int64
}

__global__ void decode_edges_kernel(const void* __restrict__ ei_raw, const int* __restrict__ flag,
                                    int* __restrict__ src_d, int* __restrict__ dst_d, int E, int n) {
    int i = blockIdx.x * blockDim.x + threadIdx.x;
    if (i >= E) return;
    int s, d;
    if (flag[0]) {
        const long long* p = (const long long*)ei_raw;
        s = (int)p[i];
        d = (int)p[(size_t)E + i];
    } else {
        const int* p = (const int*)ei_raw;
        s = p[i];
        d = p[(size_t)E + i];
    }
    // clamp defensively (reference guarantees [0, n))
    s = (s < 0) ? 0 : (s >= n ? n - 1 : s);
    d = (d < 0) ? 0 : (d >= n ? n - 1 : d);
    src_d[i] = s;
    dst_d[i] = d;
}

// ---------------- degree / normalization ----------------

__global__ void deg_count_kernel(const int* __restrict__ dst_d, float* __restrict__ deg, int E) {
    int i = blockIdx.x * blockDim.x + threadIdx.x;
    if (i < E) atomicAdd(&deg[dst_d[i]], 1.0f);
}

__global__ void deg_finish_kernel(float* __restrict__ deg, int n) {
    int i = blockIdx.x * blockDim.x + threadIdx.x;
    if (i < n) deg[i] = rsqrtf(deg[i] + 1.0f);  // +1 = self loop; deg>=1 always
}

// ---------------- dense GEMMs (fp32 vector, K=128, Ncols=128) ----------------
// Block: 256 threads; output tile 64 rows x 128 cols; W staged in two 64-row halves
// (LDS = 32KB x + 32KB w = 64KB -> 2 blocks/CU possible).

__global__ __launch_bounds__(256) void gemm1_kernel(const float* __restrict__ A,
                                                    const float* __restrict__ W,
                                                    float* __restrict__ C, int n) {
    __shared__ float xs[64 * 128];
    __shared__ float ws[64 * 128];
    const int tid = threadIdx.x;
    const int brow = blockIdx.x * 64;
    const int rows = min(64, n - brow);

    const float4* Ag = (const float4*)(A + (size_t)brow * 128);
    for (int i = tid; i < rows * 32; i += 256) ((float4*)xs)[i] = Ag[i];

    float acc[8][4] = {};
    const int tx = tid & 31, ty = tid >> 5;
    const int j0 = tx * 4, r0 = ty * 8;

    for (int kh = 0; kh < 2; ++kh) {
        __syncthreads();
        const float4* Wg = (const float4*)(W + (size_t)kh * 64 * 128);
        for (int i = tid; i < 2048; i += 256) ((float4*)ws)[i] = Wg[i];
        __syncthreads();
#pragma unroll
        for (int kk = 0; kk < 64; kk += 4) {
            float4 w0 = *(const float4*)&ws[(kk + 0) * 128 + j0];
            float4 w1 = *(const float4*)&ws[(kk + 1) * 128 + j0];
            float4 w2 = *(const float4*)&ws[(kk + 2) * 128 + j0];
            float4 w3 = *(const float4*)&ws[(kk + 3) * 128 + j0];
#pragma unroll
            for (int i = 0; i < 8; ++i) {
                float4 xv = *(const float4*)&xs[(r0 + i) * 128 + kh * 64 + kk];
                acc[i][0] += xv.x * w0.x + xv.y * w1.x + xv.z * w2.x + xv.w * w3.x;
                acc[i][1] += xv.x * w0.y + xv.y * w1.y + xv.z * w2.y + xv.w * w3.y;
                acc[i][2] += xv.x * w0.z + xv.y * w1.z + xv.z * w2.z + xv.w * w3.z;
                acc[i][3] += xv.x * w0.w + xv.y * w1.w + xv.z * w2.w + xv.w * w3.w;
            }
        }
    }
#pragma unroll
    for (int i = 0; i < 8; ++i) {
        int r = r0 + i;
        if (r < rows) {
            float4 st = make_float4(acc[i][0], acc[i][1], acc[i][2], acc[i][3]);
            *(float4*)&C[(size_t)(brow + r) * 128 + j0] = st;
        }
    }
}

// GEMM2: hagg @ Wcat + bcat, split-stored into mu (cols 0..63) and logstd (cols 64..127).
__global__ __launch_bounds__(256) void gemm2_kernel(const float* __restrict__ A,
                                                    const float* __restrict__ W,
                                                    const float* __restrict__ bias,
                                                    float* __restrict__ outMu,
                                                    float* __restrict__ outLs, int n) {
    __shared__ float xs[64 * 128];
    __shared__ float ws[64 * 128];
    const int tid = threadIdx.x;
    const int brow = blockIdx.x * 64;
    const int rows = min(64, n - brow);

    const float4* Ag = (const float4*)(A + (size_t)brow * 128);
    for (int i = tid; i < rows * 32; i += 256) ((float4*)xs)[i] = Ag[i];

    float acc[8][4] = {};
    const int tx = tid & 31, ty = tid >> 5;
    const int j0 = tx * 4, r0 = ty * 8;

    for (int kh = 0; kh < 2; ++kh) {
        __syncthreads();
        const float4* Wg = (const float4*)(W + (size_t)kh * 64 * 128);
        for (int i = tid; i < 2048; i += 256) ((float4*)ws)[i] = Wg[i];
        __syncthreads();
#pragma unroll
        for (int kk = 0; kk < 64; kk += 4) {
            float4 w0 = *(const float4*)&ws[(kk + 0) * 128 + j0];
            float4 w1 = *(const float4*)&ws[(kk + 1) * 128 + j0];
            float4 w2 = *(const float4*)&ws[(kk + 2) * 128 + j0];
            float4 w3 = *(const float4*)&ws[(kk + 3) * 128 + j0];
#pragma unroll
            for (int i = 0; i < 8; ++i) {
                float4 xv = *(const float4*)&xs[(r0 + i) * 128 + kh * 64 + kk];
                acc[i][0] += xv.x * w0.x + xv.y * w1.x + xv.z * w2.x + xv.w * w3.x;
                acc[i][1] += xv.x * w0.y + xv.y * w1.y + xv.z * w2.y + xv.w * w3.y;
                acc[i][2] += xv.x * w0.z + xv.y * w1.z + xv.z * w2.z + xv.w * w3.z;
                acc[i][3] += xv.x * w0.w + xv.y * w1.w + xv.z * w2.w + xv.w * w3.w;
            }
        }
    }
    float4 bv = *(const float4*)&bias[j0];
#pragma unroll
    for (int i = 0; i < 8; ++i) {
        int r = r0 + i;
        if (r < rows) {
            float4 st = make_float4(acc[i][0] + bv.x, acc[i][1] + bv.y,
                                    acc[i][2] + bv.z, acc[i][3] + bv.w);
            size_t gr = (size_t)(brow + r);
            if (j0 < 64)
                *(float4*)&outMu[gr * 64 + j0] = st;
            else
                *(float4*)&outLs[gr * 64 + (j0 - 64)] = st;
        }
    }
}

// ---------------- sparse aggregation (atomic scatter-add) ----------------
// One thread per (edge, 4-float chunk): 32 chunks cover the 128 features.

__global__ void aggregate_kernel(const float* __restrict__ hin, const int* __restrict__ src_d,
                                 const int* __restrict__ dst_d, const float* __restrict__ dis,
                                 float* __restrict__ hout, int E) {
    long long total = (long long)E * 32;
    long long stride = (long long)gridDim.x * blockDim.x;
    for (long long idx = (long long)blockIdx.x * blockDim.x + threadIdx.x; idx < total; idx += stride) {
        int e = (int)(idx >> 5);
        int c = ((int)idx & 31) * 4;
        int s = src_d[e], d = dst_d[e];
        float nrm = dis[s] * dis[d];
        float4 v = *(const float4*)&hin[(size_t)s * 128 + c];
        float* o = &hout[(size_t)d * 128 + c];
        atomicAdd(o + 0, v.x * nrm);
        atomicAdd(o + 1, v.y * nrm);
        atomicAdd(o + 2, v.z * nrm);
        atomicAdd(o + 3, v.w * nrm);
    }
}

// ---------------- finalize passes (self-loop fusion) ----------------

// h = relu(agg + dis^2 * hW + b1)
__global__ void finalize1_kernel(const float* __restrict__ hW, const float* __restrict__ dis,
                                 const float* __restrict__ b1, float* __restrict__ h, int n) {
    int idx = blockIdx.x * blockDim.x + threadIdx.x;
    if (idx >= n * 32) return;
    int v = idx >> 5, c = (idx & 31) * 4;
    float w = dis[v]; w *= w;
    float4 a = *(const float4*)&hW[(size_t)v * 128 + c];
    float4 cur = *(const float4*)&h[(size_t)v * 128 + c];
    float4 bb = *(const float4*)&b1[c];
    float4 o;
    o.x = fmaxf(cur.x + w * a.x + bb.x, 0.0f);
    o.y = fmaxf(cur.y + w * a.y + bb.y, 0.0f);
    o.z = fmaxf(cur.z + w * a.z + bb.z, 0.0f);
    o.w = fmaxf(cur.w + w * a.w + bb.w, 0.0f);
    *(float4*)&h[(size_t)v * 128 + c] = o;
}

// hagg += dis^2 * h   (no bias, no relu)
__global__ void finalize2_kernel(const float* __restrict__ h, const float* __restrict__ dis,
                                 float* __restrict__ hagg, int n) {
    int idx = blockIdx.x * blockDim.x + threadIdx.x;
    if (idx >= n * 32) return;
    int v = idx >> 5, c = (idx & 31) * 4;
    float w = dis[v]; w *= w;
    float4 a = *(const float4*)&h[(size_t)v * 128 + c];
    float4 cur = *(const float4*)&hagg[(size_t)v * 128 + c];
    cur.x += w * a.x;
    cur.y += w * a.y;
    cur.z += w * a.z;
    cur.w += w * a.w;
    *(float4*)&hagg[(size_t)v * 128 + c] = cur;
}

// Wcat = [Wmu | Wls], bcat = [bmu | bls]
__global__ void build_wcat_kernel(const float* __restrict__ Wmu, const float* __restrict__ Wls,
                                  const float* __restrict__ bmu, const float* __restrict__ bls,
                                  float* __restrict__ Wcat, float* __restrict__ bcat) {
    int idx = blockIdx.x * blockDim.x + threadIdx.x;
    if (idx < 128 * 128) {
        int k = idx >> 7, j = idx & 127;
        Wcat[idx] = (j < 64) ? Wmu[k * 64 + j] : Wls[k * 64 + (j - 64)];
    }
    if (idx < 128) bcat[idx] = (idx < 64) ? bmu[idx] : bls[idx - 64];
}

// ---------------- launcher ----------------

extern "C" void kernel_launch(void* const* d_in, const int* in_sizes, int n_in,
                              void* d_out, int out_size, void* d_ws, size_t ws_size,
                              hipStream_t stream) {
    const float* x   = (const float*)d_in[0];
    const void*  ei  = d_in[1];
    const float* W1  = (const float*)d_in[2];
    const float* b1  = (const float*)d_in[3];
    const float* Wmu = (const float*)d_in[4];
    const float* bmu = (const float*)d_in[5];
    const float* Wls = (const float*)d_in[6];
    const float* bls = (const float*)d_in[7];

    const int n = in_sizes[0] / 128;
    const int E = in_sizes[1] / 2;

    float* out   = (float*)d_out;
    float* outMu = out;
    float* outLs = out + (size_t)n * 64;

    char* w = (char*)d_ws;
    auto alloc = [&](size_t bytes) { char* p = w; w += align_up(bytes, 256); return p; };
    int*   flag  = (int*)  alloc(256);
    int*   src_d = (int*)  alloc((size_t)E * 4);
    int*   dst_d = (int*)  alloc((size_t)E * 4);
    float* dis   = (float*)alloc((size_t)n * 4);
    float* Wcat  = (float*)alloc(128 * 128 * 4);
    float* bcat  = (float*)alloc(128 * 4);
    float* bufA  = (float*)alloc((size_t)n * 128 * 4);  // x@W1, later A*h
    float* bufB  = (float*)alloc((size_t)n * 128 * 4);  // h

    hipMemsetAsync(dis, 0, (size_t)n * 4, stream);
    hipMemsetAsync(bufB, 0, (size_t)n * 128 * 4, stream);

    detect_i64_kernel<<<1, 256, 0, stream>>>((const int*)ei, 1024, flag);
    decode_edges_kernel<<<(E + 255) / 256, 256, 0, stream>>>(ei, flag, src_d, dst_d, E, n);
    deg_count_kernel<<<(E + 255) / 256, 256, 0, stream>>>(dst_d, dis, E);
    deg_finish_kernel<<<(n + 255) / 256, 256, 0, stream>>>(dis, n);

    const int gblocks = (n + 63) / 64;
    gemm1_kernel<<<gblocks, 256, 0, stream>>>(x, W1, bufA, n);

    aggregate_kernel<<<4096, 256, 0, stream>>>(bufA, src_d, dst_d, dis, bufB, E);
    finalize1_kernel<<<((size_t)n * 32 + 255) / 256, 256, 0, stream>>>(bufA, dis, b1, bufB, n);

    hipMemsetAsync(bufA, 0, (size_t)n * 128 * 4, stream);
    aggregate_kernel<<<4096, 256, 0, stream>>>(bufB, src_d, dst_d, dis, bufA, E);
    finalize2_kernel<<<((size_t)n * 32 + 255) / 256, 256, 0, stream>>>(bufB, dis, bufA, n);

    build_wcat_kernel<<<(128 * 128 + 255) / 256, 256, 0, stream>>>(Wmu, Wls, bmu, bls, Wcat, bcat);
    gemm2_kernel<<<gblocks, 256, 0, stream>>>(bufA, Wcat, bcat, outMu, outLs, n);
}

// Round 2
// 672.636 us; speedup vs baseline: 8.5754x; 8.5754x over previous
//
#include <hip/hip_runtime.h>
#include <hip/hip_bf16.h>
#include <stdint.h>

// GCN encoder: h = relu(A(x@W1)+b1); hagg = A h; [mu|ls] = hagg@[Wmu|Wls] + [bmu|bls]
// A = sym-normalized adjacency with self-loops. Aggregation via CSR-by-dst
// (one wave per node, register accumulation) -- no fp32 atomics.

static inline size_t align_up(size_t x, size_t a) { return (x + a - 1) / a * a; }

// ---------------- edge decode (int32 vs int64 robustness) ----------------

__global__ void detect_i64_kernel(const int* __restrict__ ei, int nwords_check, int* __restrict__ flag) {
    __shared__ int any_nz;
    if (threadIdx.x == 0) any_nz = 0;
    __syncthreads();
    int nz = 0;
    for (int i = threadIdx.x; i < nwords_check; i += blockDim.x) {
        if (ei[2 * i + 1] != 0) nz = 1;
    }
    if (nz) atomicOr(&any_nz, 1);
    __syncthreads();
    if (threadIdx.x == 0) flag[0] = any_nz ? 0 : 1;  // all-zero high words => int64
}

__device__ inline int load_idx(const void* ei, const int* flag, size_t pos, int n) {
    int v;
    if (flag[0]) v = (int)((const long long*)ei)[pos];
    else         v = ((const int*)ei)[pos];
    return (v < 0) ? 0 : (v >= n ? n - 1 : v);
}

// ---------------- degree count (int atomics, cheap) ----------------

__global__ void deg_count_kernel(const void* __restrict__ ei, const int* __restrict__ flag,
                                 int* __restrict__ deg, int E, int n) {
    int i = blockIdx.x * blockDim.x + threadIdx.x;
    if (i >= E) return;
    int d = load_idx(ei, flag, (size_t)E + i, n);
    atomicAdd(&deg[d], 1);
}

__global__ void deg_finish_kernel(const int* __restrict__ deg, float* __restrict__ dis, int n) {
    int i = blockIdx.x * blockDim.x + threadIdx.x;
    if (i < n) dis[i] = rsqrtf((float)deg[i] + 1.0f);  // +1 = self loop
}

// ---------------- exclusive prefix scan (3 phase) ----------------

__global__ void scan_blocks_kernel(const int* __restrict__ deg, int* __restrict__ excl,
                                   int* __restrict__ bsum, int n) {
    __shared__ int tmp[256];
    int i = blockIdx.x * 256 + threadIdx.x;
    int v = (i < n) ? deg[i] : 0;
    tmp[threadIdx.x] = v;
    __syncthreads();
    for (int off = 1; off < 256; off <<= 1) {
        int t = (threadIdx.x >= off) ? tmp[threadIdx.x - off] : 0;
        __syncthreads();
        tmp[threadIdx.x] += t;
        __syncthreads();
    }
    if (i < n) excl[i] = tmp[threadIdx.x] - v;
    if (threadIdx.x == 255) bsum[blockIdx.x] = tmp[255];
}

__global__ void scan_sums_kernel(int* __restrict__ bs, int nb) {
    __shared__ int tmp[1024];
    int t = threadIdx.x;
    if (nb <= 1024) {
        int v = (t < nb) ? bs[t] : 0;
        tmp[t] = v;
        __syncthreads();
        for (int off = 1; off < 1024; off <<= 1) {
            int u = (t >= off) ? tmp[t - off] : 0;
            __syncthreads();
            tmp[t] += u;
            __syncthreads();
        }
        if (t < nb) bs[t] = tmp[t] - v;  // exclusive
    } else if (t == 0) {
        int acc = 0;
        for (int i = 0; i < nb; ++i) { int v = bs[i]; bs[i] = acc; acc += v; }
    }
}

__global__ void scan_add_kernel(int* __restrict__ excl, const int* __restrict__ bsum,
                                int* __restrict__ cursor, int n) {
    int i = blockIdx.x * 256 + threadIdx.x;
    if (i < n) {
        int v = excl[i] + bsum[blockIdx.x];
        excl[i] = v;     // row_ptr (begin)
        cursor[i] = v;   // scatter cursor; after scatter == row end
    }
}

// ---------------- CSR scatter (int atomics on cursors) ----------------

__global__ void scatter_kernel(const void* __restrict__ ei, const int* __restrict__ flag,
                               const float* __restrict__ dis, int* __restrict__ cursor,
                               int* __restrict__ csr_src, float* __restrict__ csr_nrm,
                               int E, int n) {
    int i = blockIdx.x * blockDim.x + threadIdx.x;
    if (i >= E) return;
    int s = load_idx(ei, flag, i, n);
    int d = load_idx(ei, flag, (size_t)E + i, n);
    int pos = atomicAdd(&cursor[d], 1);
    csr_src[pos] = s;
    csr_nrm[pos] = dis[s] * dis[d];
}

// ---------------- fused CSR aggregation (one wave per node) ----------------
// out[v] = act( sum_e nrm_e * hin[src_e] + dis[v]^2 * hin[v] + bias )
// 64 lanes x float2 = 128 features; edge metadata is wave-uniform.

__global__ __launch_bounds__(256) void csr_agg_kernel(
        const float* __restrict__ hin, const int* __restrict__ row_beg,
        const int* __restrict__ row_end, const int* __restrict__ csr_src,
        const float* __restrict__ csr_nrm, const float* __restrict__ dis,
        const float* __restrict__ bias, float* __restrict__ out, int n, int relu) {
    int node = blockIdx.x * 4 + (threadIdx.x >> 6);
    if (node >= n) return;
    int lane = threadIdx.x & 63;
    int beg = row_beg[node], end = row_end[node];

    float2 acc = make_float2(0.0f, 0.0f);
    int e = beg;
    int s_nx = 0; float w_nx = 0.0f;
    if (e < end) { s_nx = csr_src[e]; w_nx = csr_nrm[e]; }
    while (e < end) {
        int s = s_nx; float w = w_nx;
        ++e;
        if (e < end) { s_nx = csr_src[e]; w_nx = csr_nrm[e]; }  // prefetch next edge
        float2 v = *(const float2*)&hin[(size_t)s * 128 + lane * 2];
        acc.x += v.x * w;
        acc.y += v.y * w;
    }
    float ds = dis[node]; ds *= ds;
    float2 self = *(const float2*)&hin[(size_t)node * 128 + lane * 2];
    acc.x += ds * self.x;
    acc.y += ds * self.y;
    if (bias) {
        float2 bb = *(const float2*)&bias[lane * 2];
        acc.x += bb.x; acc.y += bb.y;
    }
    if (relu) { acc.x = fmaxf(acc.x, 0.0f); acc.y = fmaxf(acc.y, 0.0f); }
    *(float2*)&out[(size_t)node * 128 + lane * 2] = acc;
}

// ---------------- dense GEMMs (fp32 vector, K=128, Ncols=128) ----------------

__global__ __launch_bounds__(256) void gemm1_kernel(const float* __restrict__ A,
                                                    const float* __restrict__ W,
                                                    float* __restrict__ C, int n) {
    __shared__ float xs[64 * 128];
    __shared__ float ws[64 * 128];
    const int tid = threadIdx.x;
    const int brow = blockIdx.x * 64;
    const int rows = min(64, n - brow);

    const float4* Ag = (const float4*)(A + (size_t)brow * 128);
    for (int i = tid; i < rows * 32; i += 256) ((float4*)xs)[i] = Ag[i];

    float acc[8][4] = {};
    const int tx = tid & 31, ty = tid >> 5;
    const int j0 = tx * 4, r0 = ty * 8;

    for (int kh = 0; kh < 2; ++kh) {
        __syncthreads();
        const float4* Wg = (const float4*)(W + (size_t)kh * 64 * 128);
        for (int i = tid; i < 2048; i += 256) ((float4*)ws)[i] = Wg[i];
        __syncthreads();
#pragma unroll
        for (int kk = 0; kk < 64; kk += 4) {
            float4 w0 = *(const float4*)&ws[(kk + 0) * 128 + j0];
            float4 w1 = *(const float4*)&ws[(kk + 1) * 128 + j0];
            float4 w2 = *(const float4*)&ws[(kk + 2) * 128 + j0];
            float4 w3 = *(const float4*)&ws[(kk + 3) * 128 + j0];
#pragma unroll
            for (int i = 0; i < 8; ++i) {
                float4 xv = *(const float4*)&xs[(r0 + i) * 128 + kh * 64 + kk];
                acc[i][0] += xv.x * w0.x + xv.y * w1.x + xv.z * w2.x + xv.w * w3.x;
                acc[i][1] += xv.x * w0.y + xv.y * w1.y + xv.z * w2.y + xv.w * w3.y;
                acc[i][2] += xv.x * w0.z + xv.y * w1.z + xv.z * w2.z + xv.w * w3.z;
                acc[i][3] += xv.x * w0.w + xv.y * w1.w + xv.z * w2.w + xv.w * w3.w;
            }
        }
    }
#pragma unroll
    for (int i = 0; i < 8; ++i) {
        int r = r0 + i;
        if (r < rows) {
            float4 st = make_float4(acc[i][0], acc[i][1], acc[i][2], acc[i][3]);
            *(float4*)&C[(size_t)(brow + r) * 128 + j0] = st;
        }
    }
}

// GEMM2: hagg @ Wcat + bcat, split-stored into mu (cols 0..63) and logstd (64..127).
__global__ __launch_bounds__(256) void gemm2_kernel(const float* __restrict__ A,
                                                    const float* __restrict__ W,
                                                    const float* __restrict__ bias,
                                                    float* __restrict__ outMu,
                                                    float* __restrict__ outLs, int n) {
    __shared__ float xs[64 * 128];
    __shared__ float ws[64 * 128];
    const int tid = threadIdx.x;
    const int brow = blockIdx.x * 64;
    const int rows = min(64, n - brow);

    const float4* Ag = (const float4*)(A + (size_t)brow * 128);
    for (int i = tid; i < rows * 32; i += 256) ((float4*)xs)[i] = Ag[i];

    float acc[8][4] = {};
    const int tx = tid & 31, ty = tid >> 5;
    const int j0 = tx * 4, r0 = ty * 8;

    for (int kh = 0; kh < 2; ++kh) {
        __syncthreads();
        const float4* Wg = (const float4*)(W + (size_t)kh * 64 * 128);
        for (int i = tid; i < 2048; i += 256) ((float4*)ws)[i] = Wg[i];
        __syncthreads();
#pragma unroll
        for (int kk = 0; kk < 64; kk += 4) {
            float4 w0 = *(const float4*)&ws[(kk + 0) * 128 + j0];
            float4 w1 = *(const float4*)&ws[(kk + 1) * 128 + j0];
            float4 w2 = *(const float4*)&ws[(kk + 2) * 128 + j0];
            float4 w3 = *(const float4*)&ws[(kk + 3) * 128 + j0];
#pragma unroll
            for (int i = 0; i < 8; ++i) {
                float4 xv = *(const float4*)&xs[(r0 + i) * 128 + kh * 64 + kk];
                acc[i][0] += xv.x * w0.x + xv.y * w1.x + xv.z * w2.x + xv.w * w3.x;
                acc[i][1] += xv.x * w0.y + xv.y * w1.y + xv.z * w2.y + xv.w * w3.y;
                acc[i][2] += xv.x * w0.z + xv.y * w1.z + xv.z * w2.z + xv.w * w3.z;
                acc[i][3] += xv.x * w0.w + xv.y * w1.w + xv.z * w2.w + xv.w * w3.w;
            }
        }
    }
    float4 bv = *(const float4*)&bias[j0];
#pragma unroll
    for (int i = 0; i < 8; ++i) {
        int r = r0 + i;
        if (r < rows) {
            float4 st = make_float4(acc[i][0] + bv.x, acc[i][1] + bv.y,
                                    acc[i][2] + bv.z, acc[i][3] + bv.w);
            size_t gr = (size_t)(brow + r);
            if (j0 < 64)
                *(float4*)&outMu[gr * 64 + j0] = st;
            else
                *(float4*)&outLs[gr * 64 + (j0 - 64)] = st;
        }
    }
}

// Wcat = [Wmu | Wls], bcat = [bmu | bls]
__global__ void build_wcat_kernel(const float* __restrict__ Wmu, const float* __restrict__ Wls,
                                  const float* __restrict__ bmu, const float* __restrict__ bls,
                                  float* __restrict__ Wcat, float* __restrict__ bcat) {
    int idx = blockIdx.x * blockDim.x + threadIdx.x;
    if (idx < 128 * 128) {
        int k = idx >> 7, j = idx & 127;
        Wcat[idx] = (j < 64) ? Wmu[k * 64 + j] : Wls[k * 64 + (j - 64)];
    }
    if (idx < 128) bcat[idx] = (idx < 64) ? bmu[idx] : bls[idx - 64];
}

// ---------------- launcher ----------------

extern "C" void kernel_launch(void* const* d_in, const int* in_sizes, int n_in,
                              void* d_out, int out_size, void* d_ws, size_t ws_size,
                              hipStream_t stream) {
    const float* x   = (const float*)d_in[0];
    const void*  ei  = d_in[1];
    const float* W1  = (const float*)d_in[2];
    const float* b1  = (const float*)d_in[3];
    const float* Wmu = (const float*)d_in[4];
    const float* bmu = (const float*)d_in[5];
    const float* Wls = (const float*)d_in[6];
    const float* bls = (const float*)d_in[7];

    const int n = in_sizes[0] / 128;
    const int E = in_sizes[1] / 2;

    float* out   = (float*)d_out;
    float* outMu = out;
    float* outLs = out + (size_t)n * 64;

    char* w = (char*)d_ws;
    auto alloc = [&](size_t bytes) { char* p = w; w += align_up(bytes, 256); return p; };
    int*   flag    = (int*)  alloc(256);
    int*   deg     = (int*)  alloc((size_t)n * 4);
    int*   row_beg = (int*)  alloc((size_t)n * 4);
    int*   cursor  = (int*)  alloc((size_t)n * 4);   // after scatter: row end
    int*   bsum    = (int*)  alloc(1024 * 4);
    float* dis     = (float*)alloc((size_t)n * 4);
    int*   csr_src = (int*)  alloc((size_t)E * 4);
    float* csr_nrm = (float*)alloc((size_t)E * 4);
    float* Wcat    = (float*)alloc(128 * 128 * 4);
    float* bcat    = (float*)alloc(128 * 4);
    float* bufA    = (float*)alloc((size_t)n * 128 * 4);  // x@W1, later hagg
    float* bufB    = (float*)alloc((size_t)n * 128 * 4);  // h

    hipMemsetAsync(deg, 0, (size_t)n * 4, stream);

    // ---- graph preprocessing: CSR by dst ----
    detect_i64_kernel<<<1, 256, 0, stream>>>((const int*)ei, 1024, flag);
    deg_count_kernel<<<(E + 255) / 256, 256, 0, stream>>>(ei, flag, deg, E, n);
    deg_finish_kernel<<<(n + 255) / 256, 256, 0, stream>>>(deg, dis, n);
    const int nb = (n + 255) / 256;
    scan_blocks_kernel<<<nb, 256, 0, stream>>>(deg, row_beg, bsum, n);
    scan_sums_kernel<<<1, 1024, 0, stream>>>(bsum, nb);
    scan_add_kernel<<<nb, 256, 0, stream>>>(row_beg, bsum, cursor, n);
    scatter_kernel<<<(E + 255) / 256, 256, 0, stream>>>(ei, flag, dis, cursor, csr_src, csr_nrm, E, n);

    // ---- layer 1: h = relu(A(x@W1) + b1) ----
    const int gblocks = (n + 63) / 64;
    gemm1_kernel<<<gblocks, 256, 0, stream>>>(x, W1, bufA, n);
    csr_agg_kernel<<<(n + 3) / 4, 256, 0, stream>>>(bufA, row_beg, cursor, csr_src, csr_nrm,
                                                    dis, b1, bufB, n, 1);

    // ---- layer 2+3: hagg = A h;  [mu|ls] = hagg @ Wcat + bcat ----
    csr_agg_kernel<<<(n + 3) / 4, 256, 0, stream>>>(bufB, row_beg, cursor, csr_src, csr_nrm,
                                                    dis, nullptr, bufA, n, 0);
    build_wcat_kernel<<<(128 * 128 + 255) / 256, 256, 0, stream>>>(Wmu, Wls, bmu, bls, Wcat, bcat);
    gemm2_kernel<<<gblocks, 256, 0, stream>>>(bufA, Wcat, bcat, outMu, outLs, n);
}